// Round 1
// baseline (6887.389 us; speedup 1.0000x reference)
//
#include <hip/hip_runtime.h>
#include <hip/hip_bf16.h>

#define NN  50000
#define EE  320000
#define E2  (EE + NN)
#define DIN 128
#define DD  256

typedef __attribute__((ext_vector_type(8))) short    bf16x8;
typedef __attribute__((ext_vector_type(4))) float    f32x4;
typedef __attribute__((ext_vector_type(4))) unsigned u32x4;

// ---------------- helpers ----------------

static __device__ __forceinline__ unsigned pk_bf16(float lo, float hi) {
  // RNE pack of two floats into two bf16 halves
  unsigned ul = __builtin_bit_cast(unsigned, lo);
  unsigned uh = __builtin_bit_cast(unsigned, hi);
  ul = (ul + 0x7fffu + ((ul >> 16) & 1u)) >> 16;
  uh = (uh + 0x7fffu + ((uh >> 16) & 1u));
  return (ul & 0xffffu) | (uh & 0xffff0000u);
}

// ---------------- weight cast fp32 -> bf16 ----------------

__global__ void k_cast(const float* __restrict__ in, unsigned short* __restrict__ out, int n) {
  int i = blockIdx.x * blockDim.x + threadIdx.x;
  if (i >= n) return;
  unsigned u = __builtin_bit_cast(unsigned, in[i]);
  out[i] = (unsigned short)((u + 0x7fffu + ((u >> 16) & 1u)) >> 16);
}

// ---------------- CSR build ----------------

__global__ void k_deg(const int* __restrict__ ei, int* __restrict__ deg) {
  int i = blockIdx.x * blockDim.x + threadIdx.x;
  if (i >= E2) return;
  int dst = (i < EE) ? ei[EE + i] : (i - EE);
  atomicAdd(&deg[dst], 1);
}

__global__ __launch_bounds__(1024) void k_scan_tile(const int* __restrict__ in,
                                                    int* __restrict__ out,
                                                    int* __restrict__ tsum, int n) {
  __shared__ int sm[1024];
  int tid = threadIdx.x;
  int g = blockIdx.x * 1024 + tid;
  sm[tid] = (g < n) ? in[g] : 0;
  __syncthreads();
  for (int off = 1; off < 1024; off <<= 1) {
    int t = (tid >= off) ? sm[tid - off] : 0;
    __syncthreads();
    sm[tid] += t;
    __syncthreads();
  }
  if (g < n) out[g] = sm[tid];
  if (tid == 1023) tsum[blockIdx.x] = sm[1023];
}

__global__ void k_scan_sums(int* __restrict__ tsum, int nb) {
  int tid = threadIdx.x;           // single wave of 64, nb <= 64
  int v = (tid < nb) ? tsum[tid] : 0;
  for (int off = 1; off < 64; off <<= 1) {
    int t = __shfl_up(v, off);
    if (tid >= off) v += t;
  }
  if (tid < nb) tsum[tid] = v;
}

__global__ void k_scan_add(int* __restrict__ out, const int* __restrict__ tsum, int n) {
  int g = blockIdx.x * blockDim.x + threadIdx.x;
  if (g >= n || g < 1024) return;
  out[g] += tsum[(g >> 10) - 1];
}

__global__ void k_scatter(const int* __restrict__ ei, const int* __restrict__ deg,
                          const int* __restrict__ inc, int* __restrict__ cur,
                          int* __restrict__ ssrc) {
  int i = blockIdx.x * blockDim.x + threadIdx.x;
  if (i >= E2) return;
  int src, dst;
  if (i < EE) { src = ei[i]; dst = ei[EE + i]; } else { src = dst = i - EE; }
  int pos = atomicAdd(&cur[dst], 1);
  ssrc[inc[dst] - deg[dst] + pos] = src;
}

// ---------------- GAT pieces ----------------

__global__ __launch_bounds__(256) void k_dots(const float* __restrict__ h,
                                              const float* __restrict__ asrc,
                                              const float* __restrict__ adst,
                                              float* __restrict__ hs, float* __restrict__ hd) {
  int node = blockIdx.x * 4 + (threadIdx.x >> 6);
  if (node >= NN) return;
  int lane = threadIdx.x & 63;
  const float* row = h + (size_t)node * DD;
  float s1 = 0.f, s2 = 0.f;
#pragma unroll
  for (int i = 0; i < 4; ++i) {
    float v = row[i * 64 + lane];
    s1 += v * asrc[i * 64 + lane];
    s2 += v * adst[i * 64 + lane];
  }
  for (int off = 32; off; off >>= 1) {
    s1 += __shfl_xor(s1, off);
    s2 += __shfl_xor(s2, off);
  }
  if (lane == 0) { hs[node] = s1; hd[node] = s2; }
}

__global__ void k_esoft(const int* __restrict__ ssrc, const int* __restrict__ deg,
                        const int* __restrict__ inc, const float* __restrict__ hs,
                        const float* __restrict__ hd, float* __restrict__ alpha) {
  int d = blockIdx.x * blockDim.x + threadIdx.x;
  if (d >= NN) return;
  int end = inc[d], cnt = deg[d], base = end - cnt;
  float hdd = hd[d];
  float m = -1e30f;
  for (int i = 0; i < cnt; ++i) {
    float s = hs[ssrc[base + i]] + hdd;
    s = (s < 0.f) ? 0.2f * s : s;
    alpha[base + i] = s;
    m = fmaxf(m, s);
  }
  float sum = 0.f;
  for (int i = 0; i < cnt; ++i) {
    float e = __expf(alpha[base + i] - m);
    alpha[base + i] = e;
    sum += e;
  }
  float inv = 1.f / sum;
  for (int i = 0; i < cnt; ++i) alpha[base + i] *= inv;
}

__global__ __launch_bounds__(256) void k_agg(const float* __restrict__ h,
                                             const int* __restrict__ ssrc,
                                             const int* __restrict__ deg,
                                             const int* __restrict__ inc,
                                             const float* __restrict__ alpha,
                                             const float* __restrict__ bias,
                                             float* __restrict__ out) {
  int d = blockIdx.x;
  int c = threadIdx.x;
  int end = inc[d], cnt = deg[d], base = end - cnt;
  float acc = 0.f;
  for (int i = 0; i < cnt; ++i) {
    int s = ssrc[base + i];
    float a = alpha[base + i];
    acc += a * h[(size_t)s * DD + c];
  }
  float v = acc + bias[c];
  out[(size_t)d * DD + c] = v > 0.f ? v : 0.f;
}

// ---------------- bf16 MFMA GEMM: C = act(A @ B^T + bias [+ R]) ----------------
// A: fp32 [M x K] lda; B: bf16 bits [N x K] row-major; C fp32 [M x N] ldc.

__global__ __launch_bounds__(256) void k_gemm(const float* __restrict__ A, int lda,
                                              const unsigned short* __restrict__ B,
                                              const float* __restrict__ bias,
                                              const float* __restrict__ R, int ldr,
                                              float* __restrict__ C, int ldc,
                                              int M, int N, int K, int act) {
  const int lane   = threadIdx.x & 63;
  const int wave   = threadIdx.x >> 6;
  const int m_lane = lane & 15;
  const int quad   = lane >> 4;
  const int n0     = blockIdx.x * 64;
  const int m0     = blockIdx.y * 64 + wave * 16;
  if (m0 >= M) return;

  int arow = m0 + m_lane;
  if (arow >= M) arow = M - 1;   // safe clamp for ragged tail; stores are guarded
  const float* Arow = A + (size_t)arow * lda;
  const unsigned short* Bb = B + (size_t)(n0 + m_lane) * K + quad * 8;
  const size_t bstep = (size_t)16 * K;

  f32x4 acc0 = {0.f, 0.f, 0.f, 0.f};
  f32x4 acc1 = {0.f, 0.f, 0.f, 0.f};
  f32x4 acc2 = {0.f, 0.f, 0.f, 0.f};
  f32x4 acc3 = {0.f, 0.f, 0.f, 0.f};

  for (int k = 0; k < K; k += 32) {
    const float4* ap = reinterpret_cast<const float4*>(Arow + k + quad * 8);
    float4 alo = ap[0];
    float4 ahi = ap[1];
    u32x4 au = {pk_bf16(alo.x, alo.y), pk_bf16(alo.z, alo.w),
                pk_bf16(ahi.x, ahi.y), pk_bf16(ahi.z, ahi.w)};
    bf16x8 afrag = __builtin_bit_cast(bf16x8, au);

    bf16x8 b0 = *reinterpret_cast<const bf16x8*>(Bb + k);
    bf16x8 b1 = *reinterpret_cast<const bf16x8*>(Bb + bstep + k);
    bf16x8 b2 = *reinterpret_cast<const bf16x8*>(Bb + 2 * bstep + k);
    bf16x8 b3 = *reinterpret_cast<const bf16x8*>(Bb + 3 * bstep + k);

    acc0 = __builtin_amdgcn_mfma_f32_16x16x32_bf16(afrag, b0, acc0, 0, 0, 0);
    acc1 = __builtin_amdgcn_mfma_f32_16x16x32_bf16(afrag, b1, acc1, 0, 0, 0);
    acc2 = __builtin_amdgcn_mfma_f32_16x16x32_bf16(afrag, b2, acc2, 0, 0, 0);
    acc3 = __builtin_amdgcn_mfma_f32_16x16x32_bf16(afrag, b3, acc3, 0, 0, 0);
  }

  f32x4 accs[4] = {acc0, acc1, acc2, acc3};
#pragma unroll
  for (int nt = 0; nt < 4; ++nt) {
    int col = n0 + nt * 16 + m_lane;
    float bv = bias ? bias[col] : 0.f;
#pragma unroll
    for (int r = 0; r < 4; ++r) {
      int row = m0 + quad * 4 + r;
      if (row < M) {
        float v = accs[nt][r] + bv;
        if (R) v += R[(size_t)row * ldr + col];
        if (act) v = v > 0.f ? v : 0.f;
        C[(size_t)row * ldc + col] = v;
      }
    }
  }
}

// ---------------- transformer pieces ----------------

__global__ void k_seqbuild(const float* __restrict__ x1, const float* __restrict__ x2,
                           const float* __restrict__ cls, const float* __restrict__ pos,
                           float* __restrict__ seqc, int n0, int cn) {
  int idx = blockIdx.x * blockDim.x + threadIdx.x;
  int total = cn * 3 * DD;
  if (idx >= total) return;
  int c = idx & (DD - 1);
  int r = idx >> 8;
  int t = r % 3, ln = r / 3;
  int n = n0 + ln;
  float v;
  if (t == 0)      v = cls[c];
  else if (t == 1) v = x1[(size_t)n * DD + c];
  else             v = x2[(size_t)n * DD + c];
  seqc[idx] = v + pos[t * DD + c];
}

__global__ __launch_bounds__(256) void k_attn(float* __restrict__ arena) {
  __shared__ float qkv[3][768];
  __shared__ float lg[4][3][3];
  __shared__ float aw[4][3][3];
  int tid = threadIdx.x;
  size_t r0 = (size_t)blockIdx.x * 3;
  for (int i = tid; i < 3 * 768; i += 256) {
    int r = i / 768, c = i % 768;
    qkv[r][c] = arena[(r0 + r) * 1024 + c];
  }
  __syncthreads();
  int h = tid >> 6, lane = tid & 63;
#pragma unroll
  for (int ti = 0; ti < 3; ++ti)
#pragma unroll
    for (int j = 0; j < 3; ++j) {
      float p = qkv[ti][h * 64 + lane] * qkv[j][256 + h * 64 + lane];
      for (int off = 32; off; off >>= 1) p += __shfl_xor(p, off);
      if (lane == 0) lg[h][ti][j] = p * 0.125f;
    }
  __syncthreads();
  if (lane < 3) {
    int ti = lane;
    float l0 = lg[h][ti][0], l1 = lg[h][ti][1], l2 = lg[h][ti][2];
    float m = fmaxf(l0, fmaxf(l1, l2));
    float e0 = __expf(l0 - m), e1 = __expf(l1 - m), e2 = __expf(l2 - m);
    float inv = 1.f / (e0 + e1 + e2);
    aw[h][ti][0] = e0 * inv; aw[h][ti][1] = e1 * inv; aw[h][ti][2] = e2 * inv;
  }
  __syncthreads();
  int c = tid;
#pragma unroll
  for (int ti = 0; ti < 3; ++ti) {
    float o = aw[h][ti][0] * qkv[0][512 + c] +
              aw[h][ti][1] * qkv[1][512 + c] +
              aw[h][ti][2] * qkv[2][512 + c];
    arena[(r0 + ti) * 1024 + 768 + c] = o;
  }
}

__global__ __launch_bounds__(256) void k_ln(float* __restrict__ buf, int rows,
                                            const float* __restrict__ g,
                                            const float* __restrict__ b) {
  int row = blockIdx.x * 4 + (threadIdx.x >> 6);
  if (row >= rows) return;
  int lane = threadIdx.x & 63;
  float* p = buf + (size_t)row * DD;
  float v[4];
  float s = 0.f, s2 = 0.f;
#pragma unroll
  for (int i = 0; i < 4; ++i) {
    v[i] = p[i * 64 + lane];
    s += v[i]; s2 += v[i] * v[i];
  }
  for (int off = 32; off; off >>= 1) { s += __shfl_xor(s, off); s2 += __shfl_xor(s2, off); }
  float mean = s * (1.f / 256.f);
  float var  = s2 * (1.f / 256.f) - mean * mean;
  float inv  = rsqrtf(var + 1e-5f);
#pragma unroll
  for (int i = 0; i < 4; ++i) {
    int c = i * 64 + lane;
    p[c] = (v[i] - mean) * inv * g[c] + b[c];
  }
}

__global__ __launch_bounds__(256) void k_final(const float* __restrict__ seqc, int n0, int cn,
                                               const float* __restrict__ g,
                                               const float* __restrict__ b,
                                               float* __restrict__ out) {
  int ln = blockIdx.x * 4 + (threadIdx.x >> 6);
  if (ln >= cn) return;
  int lane = threadIdx.x & 63;
  const float* p = seqc + (size_t)ln * 3 * DD;   // token 0 row
  float v[4];
  float s = 0.f, s2 = 0.f;
#pragma unroll
  for (int i = 0; i < 4; ++i) {
    v[i] = p[i * 64 + lane];
    s += v[i]; s2 += v[i] * v[i];
  }
  for (int off = 32; off; off >>= 1) { s += __shfl_xor(s, off); s2 += __shfl_xor(s2, off); }
  float mean = s * (1.f / 256.f);
  float var  = s2 * (1.f / 256.f) - mean * mean;
  float inv  = rsqrtf(var + 1e-5f);
#pragma unroll
  for (int i = 0; i < 4; ++i) {
    int c = i * 64 + lane;
    out[(size_t)(n0 + ln) * DD + c] = (v[i] - mean) * inv * g[c] + b[c];
  }
}

// ---------------- host ----------------

extern "C" void kernel_launch(void* const* d_in, const int* in_sizes, int n_in,
                              void* d_out, int out_size, void* d_ws, size_t ws_size,
                              hipStream_t stream) {
  const float* x       = (const float*)d_in[0];
  const int*   ei      = (const int*)d_in[1];
  const float* gat1_W  = (const float*)d_in[2];
  const float* gat1_b  = (const float*)d_in[3];
  const float* gat1_as = (const float*)d_in[4];
  const float* gat1_ad = (const float*)d_in[5];
  const float* gat2_W  = (const float*)d_in[6];
  const float* gat2_b  = (const float*)d_in[7];
  const float* gat2_as = (const float*)d_in[8];
  const float* gat2_ad = (const float*)d_in[9];
  const float* cls     = (const float*)d_in[10];
  const float* pos     = (const float*)d_in[11];
  const float* Wqkv    = (const float*)d_in[12];
  const float* bqkv    = (const float*)d_in[13];
  const float* Wo      = (const float*)d_in[14];
  const float* bo      = (const float*)d_in[15];
  const float* ln1_g   = (const float*)d_in[16];
  const float* ln1_b   = (const float*)d_in[17];
  const float* ln2_g   = (const float*)d_in[18];
  const float* ln2_b   = (const float*)d_in[19];
  const float* Wff1    = (const float*)d_in[20];
  const float* bff1    = (const float*)d_in[21];
  const float* Wff2    = (const float*)d_in[22];
  const float* bff2    = (const float*)d_in[23];
  const float* norm_g  = (const float*)d_in[24];
  const float* norm_b  = (const float*)d_in[25];
  float* out = (float*)d_out;

  char* ws = (char*)d_ws;
  size_t off = 0;
  auto alloc = [&](size_t bytes) -> void* {
    off = (off + 255) & ~(size_t)255;
    void* p = ws + off;
    off += bytes;
    return p;
  };

  unsigned short* wb_g1  = (unsigned short*)alloc(sizeof(unsigned short) * 256 * 128);
  unsigned short* wb_g2  = (unsigned short*)alloc(sizeof(unsigned short) * 256 * 256);
  unsigned short* wb_qkv = (unsigned short*)alloc(sizeof(unsigned short) * 2 * 768 * 256);
  unsigned short* wb_o   = (unsigned short*)alloc(sizeof(unsigned short) * 2 * 256 * 256);
  unsigned short* wb_f1  = (unsigned short*)alloc(sizeof(unsigned short) * 2 * 1024 * 256);
  unsigned short* wb_f2  = (unsigned short*)alloc(sizeof(unsigned short) * 2 * 256 * 1024);
  float* h   = (float*)alloc(sizeof(float) * (size_t)NN * DD);
  float* x1  = (float*)alloc(sizeof(float) * (size_t)NN * DD);
  float* x2  = (float*)alloc(sizeof(float) * (size_t)NN * DD);
  float* hs  = (float*)alloc(sizeof(float) * NN);
  float* hd  = (float*)alloc(sizeof(float) * NN);
  int* deg   = (int*)alloc(sizeof(int) * NN);
  int* inc   = (int*)alloc(sizeof(int) * NN);
  int* cur   = (int*)alloc(sizeof(int) * NN);
  int* tsum  = (int*)alloc(sizeof(int) * 64);
  int* ssrc  = (int*)alloc(sizeof(int) * E2);
  float* alpha = (float*)alloc(sizeof(float) * E2);

  // chunk the transformer to fit ws
  size_t fixed = (off + 255) & ~(size_t)255;
  size_t rem = (ws_size > fixed + 4096) ? (ws_size - fixed - 4096) : 0;
  const size_t per_node = (size_t)3 * DD * 4 + (size_t)3 * 1024 * 4;  // seqc + arena
  size_t cn_max = rem / per_node;
  if (cn_max < 1) cn_max = 1;
  if (cn_max > NN) cn_max = NN;
  int nc = (int)((NN + cn_max - 1) / cn_max);
  int cn = (NN + nc - 1) / nc;
  float* seqc  = (float*)alloc(sizeof(float) * (size_t)3 * cn * DD);
  float* arena = (float*)alloc(sizeof(float) * (size_t)3 * cn * 1024);

  // ---- weight casts ----
  auto cast = [&](const float* src, unsigned short* dst, int n) {
    k_cast<<<(n + 255) / 256, 256, 0, stream>>>(src, dst, n);
  };
  cast(gat1_W, wb_g1, 256 * 128);
  cast(gat2_W, wb_g2, 256 * 256);
  cast(Wqkv, wb_qkv, 2 * 768 * 256);
  cast(Wo, wb_o, 2 * 256 * 256);
  cast(Wff1, wb_f1, 2 * 1024 * 256);
  cast(Wff2, wb_f2, 2 * 256 * 1024);

  // ---- CSR build ----
  hipMemsetAsync(deg, 0, sizeof(int) * NN, stream);
  hipMemsetAsync(cur, 0, sizeof(int) * NN, stream);
  k_deg<<<(E2 + 255) / 256, 256, 0, stream>>>(ei, deg);
  int nb = (NN + 1023) / 1024;
  k_scan_tile<<<nb, 1024, 0, stream>>>(deg, inc, tsum, NN);
  k_scan_sums<<<1, 64, 0, stream>>>(tsum, nb);
  k_scan_add<<<(NN + 255) / 256, 256, 0, stream>>>(inc, tsum, NN);
  k_scatter<<<(E2 + 255) / 256, 256, 0, stream>>>(ei, deg, inc, cur, ssrc);

  auto gemm = [&](const float* A, int lda, const unsigned short* B, const float* bias,
                  const float* R, int ldr, float* C, int ldc, int M, int N, int K, int act) {
    dim3 grid(N / 64, (M + 63) / 64);
    k_gemm<<<grid, 256, 0, stream>>>(A, lda, B, bias, R, ldr, C, ldc, M, N, K, act);
  };

  // ---- GAT layer 1 ----
  gemm(x, DIN, wb_g1, nullptr, nullptr, 0, h, DD, NN, DD, DIN, 0);
  k_dots<<<(NN + 3) / 4, 256, 0, stream>>>(h, gat1_as, gat1_ad, hs, hd);
  k_esoft<<<(NN + 255) / 256, 256, 0, stream>>>(ssrc, deg, inc, hs, hd, alpha);
  k_agg<<<NN, 256, 0, stream>>>(h, ssrc, deg, inc, alpha, gat1_b, x1);

  // ---- GAT layer 2 ----
  gemm(x1, DD, wb_g2, nullptr, nullptr, 0, h, DD, NN, DD, DD, 0);
  k_dots<<<(NN + 3) / 4, 256, 0, stream>>>(h, gat2_as, gat2_ad, hs, hd);
  k_esoft<<<(NN + 255) / 256, 256, 0, stream>>>(ssrc, deg, inc, hs, hd, alpha);
  k_agg<<<NN, 256, 0, stream>>>(h, ssrc, deg, inc, alpha, gat2_b, x2);

  // ---- transformer (chunked over nodes) ----
  for (int n0 = 0; n0 < NN; n0 += cn) {
    int c = NN - n0 < cn ? NN - n0 : cn;
    int Mch = 3 * c;
    k_seqbuild<<<(c * 3 * DD + 255) / 256, 256, 0, stream>>>(x1, x2, cls, pos, seqc, n0, c);
    for (int l = 0; l < 2; ++l) {
      gemm(seqc, DD, wb_qkv + (size_t)l * 768 * 256, bqkv + l * 768,
           nullptr, 0, arena, 1024, Mch, 768, DD, 0);
      k_attn<<<c, 256, 0, stream>>>(arena);
      gemm(arena + 768, 1024, wb_o + (size_t)l * 256 * 256, bo + l * 256,
           seqc, DD, seqc, DD, Mch, DD, DD, 0);
      k_ln<<<(Mch + 3) / 4, 256, 0, stream>>>(seqc, Mch, ln1_g + l * 256, ln1_b + l * 256);
      gemm(seqc, DD, wb_f1 + (size_t)l * 1024 * 256, bff1 + l * 1024,
           nullptr, 0, arena, 1024, Mch, 1024, DD, 1);
      gemm(arena, 1024, wb_f2 + (size_t)l * 256 * 1024, bff2 + l * 256,
           seqc, DD, seqc, DD, Mch, DD, 1024, 0);
      k_ln<<<(Mch + 3) / 4, 256, 0, stream>>>(seqc, Mch, ln2_g + l * 256, ln2_b + l * 256);
    }
    k_final<<<(c + 3) / 4, 256, 0, stream>>>(seqc, n0, c, norm_g, norm_b, out);
  }
}

// Round 2
// 4210.202 us; speedup vs baseline: 1.6359x; 1.6359x over previous
//
#include <hip/hip_runtime.h>
#include <hip/hip_bf16.h>

#define NN  50000
#define EE  320000
#define E2  (EE + NN)
#define DIN 128
#define DD  256

typedef __attribute__((ext_vector_type(8))) short    bf16x8;
typedef __attribute__((ext_vector_type(4))) float    f32x4;
typedef __attribute__((ext_vector_type(4))) unsigned u32x4;

// ---------------- helpers ----------------

static __device__ __forceinline__ unsigned pk_bf16(float lo, float hi) {
  unsigned ul = __builtin_bit_cast(unsigned, lo);
  unsigned uh = __builtin_bit_cast(unsigned, hi);
  ul = (ul + 0x7fffu + ((ul >> 16) & 1u)) >> 16;
  uh = (uh + 0x7fffu + ((uh >> 16) & 1u));
  return (ul & 0xffffu) | (uh & 0xffff0000u);
}

static __device__ __forceinline__ float bf2f(unsigned short u) {
  return __builtin_bit_cast(float, (unsigned)u << 16);
}

static __device__ __forceinline__ unsigned short f2bf(float f) {
  unsigned u = __builtin_bit_cast(unsigned, f);
  return (unsigned short)((u + 0x7fffu + ((u >> 16) & 1u)) >> 16);
}

// ---------------- weight cast fp32 -> bf16 ----------------

__global__ void k_cast(const float* __restrict__ in, unsigned short* __restrict__ out, int n) {
  int i = blockIdx.x * blockDim.x + threadIdx.x;
  if (i >= n) return;
  out[i] = f2bf(in[i]);
}

// ---------------- CSR build ----------------

__global__ void k_deg(const int* __restrict__ ei, int* __restrict__ deg) {
  int i = blockIdx.x * blockDim.x + threadIdx.x;
  if (i >= E2) return;
  int dst = (i < EE) ? ei[EE + i] : (i - EE);
  atomicAdd(&deg[dst], 1);
}

__global__ __launch_bounds__(1024) void k_scan_tile(const int* __restrict__ in,
                                                    int* __restrict__ out,
                                                    int* __restrict__ tsum, int n) {
  __shared__ int sm[1024];
  int tid = threadIdx.x;
  int g = blockIdx.x * 1024 + tid;
  sm[tid] = (g < n) ? in[g] : 0;
  __syncthreads();
  for (int off = 1; off < 1024; off <<= 1) {
    int t = (tid >= off) ? sm[tid - off] : 0;
    __syncthreads();
    sm[tid] += t;
    __syncthreads();
  }
  if (g < n) out[g] = sm[tid];
  if (tid == 1023) tsum[blockIdx.x] = sm[1023];
}

__global__ void k_scan_sums(int* __restrict__ tsum, int nb) {
  int tid = threadIdx.x;           // single wave of 64, nb <= 64
  int v = (tid < nb) ? tsum[tid] : 0;
  for (int off = 1; off < 64; off <<= 1) {
    int t = __shfl_up(v, off);
    if (tid >= off) v += t;
  }
  if (tid < nb) tsum[tid] = v;
}

__global__ void k_scan_add(int* __restrict__ out, const int* __restrict__ tsum, int n) {
  int g = blockIdx.x * blockDim.x + threadIdx.x;
  if (g >= n || g < 1024) return;
  out[g] += tsum[(g >> 10) - 1];
}

__global__ void k_scatter(const int* __restrict__ ei, const int* __restrict__ deg,
                          const int* __restrict__ inc, int* __restrict__ cur,
                          int* __restrict__ ssrc) {
  int i = blockIdx.x * blockDim.x + threadIdx.x;
  if (i >= E2) return;
  int src, dst;
  if (i < EE) { src = ei[i]; dst = ei[EE + i]; } else { src = dst = i - EE; }
  int pos = atomicAdd(&cur[dst], 1);
  ssrc[inc[dst] - deg[dst] + pos] = src;
}

// ---------------- GAT pieces ----------------

__global__ __launch_bounds__(256) void k_dots(const float* __restrict__ h,
                                              const float* __restrict__ asrc,
                                              const float* __restrict__ adst,
                                              float* __restrict__ hs, float* __restrict__ hd) {
  int node = blockIdx.x * 4 + (threadIdx.x >> 6);
  if (node >= NN) return;
  int lane = threadIdx.x & 63;
  const float* row = h + (size_t)node * DD;
  float s1 = 0.f, s2 = 0.f;
#pragma unroll
  for (int i = 0; i < 4; ++i) {
    float v = row[i * 64 + lane];
    s1 += v * asrc[i * 64 + lane];
    s2 += v * adst[i * 64 + lane];
  }
  for (int off = 32; off; off >>= 1) {
    s1 += __shfl_xor(s1, off);
    s2 += __shfl_xor(s2, off);
  }
  if (lane == 0) { hs[node] = s1; hd[node] = s2; }
}

__global__ void k_esoft(const int* __restrict__ ssrc, const int* __restrict__ deg,
                        const int* __restrict__ inc, const float* __restrict__ hs,
                        const float* __restrict__ hd, float* __restrict__ alpha) {
  int d = blockIdx.x * blockDim.x + threadIdx.x;
  if (d >= NN) return;
  int end = inc[d], cnt = deg[d], base = end - cnt;
  float hdd = hd[d];
  float m = -1e30f;
  for (int i = 0; i < cnt; ++i) {
    float s = hs[ssrc[base + i]] + hdd;
    s = (s < 0.f) ? 0.2f * s : s;
    alpha[base + i] = s;
    m = fmaxf(m, s);
  }
  float sum = 0.f;
  for (int i = 0; i < cnt; ++i) {
    float e = __expf(alpha[base + i] - m);
    alpha[base + i] = e;
    sum += e;
  }
  float inv = 1.f / sum;
  for (int i = 0; i < cnt; ++i) alpha[base + i] *= inv;
}

__global__ __launch_bounds__(256) void k_agg(const float* __restrict__ h,
                                             const int* __restrict__ ssrc,
                                             const int* __restrict__ deg,
                                             const int* __restrict__ inc,
                                             const float* __restrict__ alpha,
                                             const float* __restrict__ bias,
                                             float* __restrict__ out) {
  int d = blockIdx.x;
  int c = threadIdx.x;
  int end = inc[d], cnt = deg[d], base = end - cnt;
  float acc = 0.f;
  for (int i = 0; i < cnt; ++i) {
    int s = ssrc[base + i];
    float a = alpha[base + i];
    acc += a * h[(size_t)s * DD + c];
  }
  float v = acc + bias[c];
  out[(size_t)d * DD + c] = v > 0.f ? v : 0.f;
}

// ---------------- fp32-A bf16 MFMA GEMM (GAT): C_f32 = relu?(A @ B^T) ----------------

__global__ __launch_bounds__(256) void k_gemm(const float* __restrict__ A, int lda,
                                              const unsigned short* __restrict__ B,
                                              float* __restrict__ C, int ldc,
                                              int M, int N, int K) {
  const int lane   = threadIdx.x & 63;
  const int wave   = threadIdx.x >> 6;
  const int m_lane = lane & 15;
  const int quad   = lane >> 4;
  const int n0     = blockIdx.x * 64;
  const int m0     = blockIdx.y * 64 + wave * 16;
  if (m0 >= M) return;

  int arow = m0 + m_lane;
  if (arow >= M) arow = M - 1;
  const float* Arow = A + (size_t)arow * lda;
  const unsigned short* Bb = B + (size_t)(n0 + m_lane) * K + quad * 8;
  const size_t bstep = (size_t)16 * K;

  f32x4 acc[4] = {};

  for (int k = 0; k < K; k += 32) {
    const float4* ap = reinterpret_cast<const float4*>(Arow + k + quad * 8);
    float4 alo = ap[0];
    float4 ahi = ap[1];
    u32x4 au = {pk_bf16(alo.x, alo.y), pk_bf16(alo.z, alo.w),
                pk_bf16(ahi.x, ahi.y), pk_bf16(ahi.z, ahi.w)};
    bf16x8 afrag = __builtin_bit_cast(bf16x8, au);
#pragma unroll
    for (int j = 0; j < 4; ++j) {
      bf16x8 bj = *reinterpret_cast<const bf16x8*>(Bb + j * bstep + k);
      acc[j] = __builtin_amdgcn_mfma_f32_16x16x32_bf16(afrag, bj, acc[j], 0, 0, 0);
    }
  }

#pragma unroll
  for (int nt = 0; nt < 4; ++nt) {
    int col = n0 + nt * 16 + m_lane;
#pragma unroll
    for (int r = 0; r < 4; ++r) {
      int row = m0 + quad * 4 + r;
      if (row < M) C[(size_t)row * ldc + col] = acc[nt][r];
    }
  }
}

// ---------------- bf16-A bf16 GEMM: C_bf16 = act(A @ B^T + bias [+ R]) ----------------
// A: bf16 [M x K] lda; B: bf16 [N x K]; C bf16 [M x N] ldc; R optional bf16.

__global__ __launch_bounds__(256) void k_gemm_bf(const unsigned short* __restrict__ A, int lda,
                                                 const unsigned short* __restrict__ B,
                                                 const float* __restrict__ bias,
                                                 const unsigned short* __restrict__ R, int ldr,
                                                 unsigned short* __restrict__ C, int ldc,
                                                 int M, int N, int K, int act) {
  const int lane   = threadIdx.x & 63;
  const int wave   = threadIdx.x >> 6;
  const int m_lane = lane & 15;
  const int quad   = lane >> 4;
  const int n0     = blockIdx.x * 64;
  const int m0     = blockIdx.y * 128 + wave * 32;
  if (m0 >= M) return;

  int r0 = m0 + m_lane;      if (r0 >= M) r0 = M - 1;
  int r1 = m0 + 16 + m_lane; if (r1 >= M) r1 = M - 1;
  const unsigned short* A0 = A + (size_t)r0 * lda + quad * 8;
  const unsigned short* A1 = A + (size_t)r1 * lda + quad * 8;
  const unsigned short* Bb = B + (size_t)(n0 + m_lane) * K + quad * 8;
  const size_t bstep = (size_t)16 * K;

  f32x4 acc[2][4] = {};

  for (int k = 0; k < K; k += 32) {
    bf16x8 a0 = *reinterpret_cast<const bf16x8*>(A0 + k);
    bf16x8 a1 = *reinterpret_cast<const bf16x8*>(A1 + k);
#pragma unroll
    for (int j = 0; j < 4; ++j) {
      bf16x8 bj = *reinterpret_cast<const bf16x8*>(Bb + j * bstep + k);
      acc[0][j] = __builtin_amdgcn_mfma_f32_16x16x32_bf16(a0, bj, acc[0][j], 0, 0, 0);
      acc[1][j] = __builtin_amdgcn_mfma_f32_16x16x32_bf16(a1, bj, acc[1][j], 0, 0, 0);
    }
  }

#pragma unroll
  for (int mi = 0; mi < 2; ++mi)
#pragma unroll
    for (int nt = 0; nt < 4; ++nt) {
      int col = n0 + nt * 16 + m_lane;
      float bv = bias ? bias[col] : 0.f;
#pragma unroll
      for (int r = 0; r < 4; ++r) {
        int row = m0 + mi * 16 + quad * 4 + r;
        if (row < M) {
          float v = acc[mi][nt][r] + bv;
          if (R) v += bf2f(R[(size_t)row * ldr + col]);
          if (act) v = v > 0.f ? v : 0.f;
          C[(size_t)row * ldc + col] = f2bf(v);
        }
      }
    }
}

// ---------------- transformer pieces (bf16 activations) ----------------

__global__ void k_seqbuild(const float* __restrict__ x1, const float* __restrict__ x2,
                           const float* __restrict__ cls, const float* __restrict__ pos,
                           unsigned short* __restrict__ seqc, int n0, int cn) {
  int idx = blockIdx.x * blockDim.x + threadIdx.x;
  int total = cn * 3 * DD;
  if (idx >= total) return;
  int c = idx & (DD - 1);
  int r = idx >> 8;
  int t = r % 3, ln = r / 3;
  int n = n0 + ln;
  float v;
  if (t == 0)      v = cls[c];
  else if (t == 1) v = x1[(size_t)n * DD + c];
  else             v = x2[(size_t)n * DD + c];
  seqc[idx] = f2bf(v + pos[t * DD + c]);
}

__global__ __launch_bounds__(256) void k_attn(unsigned short* __restrict__ arena) {
  __shared__ float qkv[3][768];
  __shared__ float lg[4][3][3];
  __shared__ float aw[4][3][3];
  int tid = threadIdx.x;
  size_t r0 = (size_t)blockIdx.x * 3;
  for (int i = tid; i < 3 * 768; i += 256) {
    int r = i / 768, c = i % 768;
    qkv[r][c] = bf2f(arena[(r0 + r) * 1024 + c]);
  }
  __syncthreads();
  int h = tid >> 6, lane = tid & 63;
#pragma unroll
  for (int ti = 0; ti < 3; ++ti)
#pragma unroll
    for (int j = 0; j < 3; ++j) {
      float p = qkv[ti][h * 64 + lane] * qkv[j][256 + h * 64 + lane];
      for (int off = 32; off; off >>= 1) p += __shfl_xor(p, off);
      if (lane == 0) lg[h][ti][j] = p * 0.125f;
    }
  __syncthreads();
  if (lane < 3) {
    int ti = lane;
    float l0 = lg[h][ti][0], l1 = lg[h][ti][1], l2 = lg[h][ti][2];
    float m = fmaxf(l0, fmaxf(l1, l2));
    float e0 = __expf(l0 - m), e1 = __expf(l1 - m), e2 = __expf(l2 - m);
    float inv = 1.f / (e0 + e1 + e2);
    aw[h][ti][0] = e0 * inv; aw[h][ti][1] = e1 * inv; aw[h][ti][2] = e2 * inv;
  }
  __syncthreads();
  int c = tid;
#pragma unroll
  for (int ti = 0; ti < 3; ++ti) {
    float o = aw[h][ti][0] * qkv[0][512 + c] +
              aw[h][ti][1] * qkv[1][512 + c] +
              aw[h][ti][2] * qkv[2][512 + c];
    arena[(r0 + ti) * 1024 + 768 + c] = f2bf(o);
  }
}

__global__ __launch_bounds__(256) void k_ln(unsigned short* __restrict__ buf, int rows,
                                            const float* __restrict__ g,
                                            const float* __restrict__ b) {
  int row = blockIdx.x * 4 + (threadIdx.x >> 6);
  if (row >= rows) return;
  int lane = threadIdx.x & 63;
  unsigned short* p = buf + (size_t)row * DD;
  float v[4];
  float s = 0.f, s2 = 0.f;
#pragma unroll
  for (int i = 0; i < 4; ++i) {
    v[i] = bf2f(p[i * 64 + lane]);
    s += v[i]; s2 += v[i] * v[i];
  }
  for (int off = 32; off; off >>= 1) { s += __shfl_xor(s, off); s2 += __shfl_xor(s2, off); }
  float mean = s * (1.f / 256.f);
  float var  = s2 * (1.f / 256.f) - mean * mean;
  float inv  = rsqrtf(var + 1e-5f);
#pragma unroll
  for (int i = 0; i < 4; ++i) {
    int c = i * 64 + lane;
    p[c] = f2bf((v[i] - mean) * inv * g[c] + b[c]);
  }
}

__global__ __launch_bounds__(256) void k_final(const unsigned short* __restrict__ seqc,
                                               int n0, int cn,
                                               const float* __restrict__ g,
                                               const float* __restrict__ b,
                                               float* __restrict__ out) {
  int ln = blockIdx.x * 4 + (threadIdx.x >> 6);
  if (ln >= cn) return;
  int lane = threadIdx.x & 63;
  const unsigned short* p = seqc + (size_t)ln * 3 * DD;   // token 0 row
  float v[4];
  float s = 0.f, s2 = 0.f;
#pragma unroll
  for (int i = 0; i < 4; ++i) {
    v[i] = bf2f(p[i * 64 + lane]);
    s += v[i]; s2 += v[i] * v[i];
  }
  for (int off = 32; off; off >>= 1) { s += __shfl_xor(s, off); s2 += __shfl_xor(s2, off); }
  float mean = s * (1.f / 256.f);
  float var  = s2 * (1.f / 256.f) - mean * mean;
  float inv  = rsqrtf(var + 1e-5f);
#pragma unroll
  for (int i = 0; i < 4; ++i) {
    int c = i * 64 + lane;
    out[(size_t)(n0 + ln) * DD + c] = (v[i] - mean) * inv * g[c] + b[c];
  }
}

// ---------------- GAT epilogue pieces need bias+relu on fp32 h path ----------------
// (k_agg already applies bias+relu; k_gemm outputs raw h.)

// ---------------- host ----------------

extern "C" void kernel_launch(void* const* d_in, const int* in_sizes, int n_in,
                              void* d_out, int out_size, void* d_ws, size_t ws_size,
                              hipStream_t stream) {
  const float* x       = (const float*)d_in[0];
  const int*   ei      = (const int*)d_in[1];
  const float* gat1_W  = (const float*)d_in[2];
  const float* gat1_b  = (const float*)d_in[3];
  const float* gat1_as = (const float*)d_in[4];
  const float* gat1_ad = (const float*)d_in[5];
  const float* gat2_W  = (const float*)d_in[6];
  const float* gat2_b  = (const float*)d_in[7];
  const float* gat2_as = (const float*)d_in[8];
  const float* gat2_ad = (const float*)d_in[9];
  const float* cls     = (const float*)d_in[10];
  const float* pos     = (const float*)d_in[11];
  const float* Wqkv    = (const float*)d_in[12];
  const float* bqkv    = (const float*)d_in[13];
  const float* Wo      = (const float*)d_in[14];
  const float* bo      = (const float*)d_in[15];
  const float* ln1_g   = (const float*)d_in[16];
  const float* ln1_b   = (const float*)d_in[17];
  const float* ln2_g   = (const float*)d_in[18];
  const float* ln2_b   = (const float*)d_in[19];
  const float* Wff1    = (const float*)d_in[20];
  const float* bff1    = (const float*)d_in[21];
  const float* Wff2    = (const float*)d_in[22];
  const float* bff2    = (const float*)d_in[23];
  const float* norm_g  = (const float*)d_in[24];
  const float* norm_b  = (const float*)d_in[25];
  float* out = (float*)d_out;

  char* ws = (char*)d_ws;
  size_t off = 0;
  auto alloc = [&](size_t bytes) -> void* {
    off = (off + 255) & ~(size_t)255;
    void* p = ws + off;
    off += bytes;
    return p;
  };

  unsigned short* wb_g1  = (unsigned short*)alloc(sizeof(unsigned short) * 256 * 128);
  unsigned short* wb_g2  = (unsigned short*)alloc(sizeof(unsigned short) * 256 * 256);
  unsigned short* wb_qkv = (unsigned short*)alloc(sizeof(unsigned short) * 2 * 768 * 256);
  unsigned short* wb_o   = (unsigned short*)alloc(sizeof(unsigned short) * 2 * 256 * 256);
  unsigned short* wb_f1  = (unsigned short*)alloc(sizeof(unsigned short) * 2 * 1024 * 256);
  unsigned short* wb_f2  = (unsigned short*)alloc(sizeof(unsigned short) * 2 * 256 * 1024);
  float* h   = (float*)alloc(sizeof(float) * (size_t)NN * DD);
  float* x1  = (float*)alloc(sizeof(float) * (size_t)NN * DD);
  float* x2  = (float*)alloc(sizeof(float) * (size_t)NN * DD);
  float* hs  = (float*)alloc(sizeof(float) * NN);
  float* hd  = (float*)alloc(sizeof(float) * NN);
  int* deg   = (int*)alloc(sizeof(int) * NN);
  int* inc   = (int*)alloc(sizeof(int) * NN);
  int* cur   = (int*)alloc(sizeof(int) * NN);
  int* tsum  = (int*)alloc(sizeof(int) * 64);
  int* ssrc  = (int*)alloc(sizeof(int) * E2);
  float* alpha = (float*)alloc(sizeof(float) * E2);

  // chunk the transformer to fit ws AND stay L3-resident (~192 MB @ cn=25000)
  size_t fixed = (off + 255) & ~(size_t)255;
  size_t rem = (ws_size > fixed + 4096) ? (ws_size - fixed - 4096) : 0;
  const size_t per_node = (size_t)3 * DD * 2 + (size_t)3 * 1024 * 2;  // seqc + arena, bf16
  size_t cn_max = rem / per_node;
  if (cn_max < 1) cn_max = 1;
  if (cn_max > 25000) cn_max = 25000;           // L3-residency cap
  int nc = (int)((NN + cn_max - 1) / cn_max);
  int cn = (NN + nc - 1) / nc;
  unsigned short* seqc  = (unsigned short*)alloc(sizeof(unsigned short) * (size_t)3 * cn * DD);
  unsigned short* arena = (unsigned short*)alloc(sizeof(unsigned short) * (size_t)3 * cn * 1024);

  // ---- weight casts ----
  auto cast = [&](const float* src, unsigned short* dst, int n) {
    k_cast<<<(n + 255) / 256, 256, 0, stream>>>(src, dst, n);
  };
  cast(gat1_W, wb_g1, 256 * 128);
  cast(gat2_W, wb_g2, 256 * 256);
  cast(Wqkv, wb_qkv, 2 * 768 * 256);
  cast(Wo, wb_o, 2 * 256 * 256);
  cast(Wff1, wb_f1, 2 * 1024 * 256);
  cast(Wff2, wb_f2, 2 * 256 * 1024);

  // ---- CSR build ----
  hipMemsetAsync(deg, 0, sizeof(int) * NN, stream);
  hipMemsetAsync(cur, 0, sizeof(int) * NN, stream);
  k_deg<<<(E2 + 255) / 256, 256, 0, stream>>>(ei, deg);
  int nb = (NN + 1023) / 1024;
  k_scan_tile<<<nb, 1024, 0, stream>>>(deg, inc, tsum, NN);
  k_scan_sums<<<1, 64, 0, stream>>>(tsum, nb);
  k_scan_add<<<(NN + 255) / 256, 256, 0, stream>>>(inc, tsum, NN);
  k_scatter<<<(E2 + 255) / 256, 256, 0, stream>>>(ei, deg, inc, cur, ssrc);

  // ---- GAT layer 1 ----
  {
    dim3 grid(DD / 64, (NN + 63) / 64);
    k_gemm<<<grid, 256, 0, stream>>>(x, DIN, wb_g1, h, DD, NN, DD, DIN);
  }
  k_dots<<<(NN + 3) / 4, 256, 0, stream>>>(h, gat1_as, gat1_ad, hs, hd);
  k_esoft<<<(NN + 255) / 256, 256, 0, stream>>>(ssrc, deg, inc, hs, hd, alpha);
  k_agg<<<NN, 256, 0, stream>>>(h, ssrc, deg, inc, alpha, gat1_b, x1);

  // ---- GAT layer 2 ----
  {
    dim3 grid(DD / 64, (NN + 63) / 64);
    k_gemm<<<grid, 256, 0, stream>>>(x1, DD, wb_g2, h, DD, NN, DD, DD);
  }
  k_dots<<<(NN + 3) / 4, 256, 0, stream>>>(h, gat2_as, gat2_ad, hs, hd);
  k_esoft<<<(NN + 255) / 256, 256, 0, stream>>>(ssrc, deg, inc, hs, hd, alpha);
  k_agg<<<NN, 256, 0, stream>>>(h, ssrc, deg, inc, alpha, gat2_b, x2);

  auto gemm_bf = [&](const unsigned short* A, int lda, const unsigned short* B,
                     const float* bias, const unsigned short* R, int ldr,
                     unsigned short* C, int ldc, int M, int N, int K, int act) {
    dim3 grid(N / 64, (M + 127) / 128);
    k_gemm_bf<<<grid, 256, 0, stream>>>(A, lda, B, bias, R, ldr, C, ldc, M, N, K, act);
  };

  // ---- transformer (chunked over nodes; chunk stays L3-resident) ----
  for (int n0 = 0; n0 < NN; n0 += cn) {
    int c = NN - n0 < cn ? NN - n0 : cn;
    int Mch = 3 * c;
    k_seqbuild<<<(c * 3 * DD + 255) / 256, 256, 0, stream>>>(x1, x2, cls, pos, seqc, n0, c);
    for (int l = 0; l < 2; ++l) {
      gemm_bf(seqc, DD, wb_qkv + (size_t)l * 768 * 256, bqkv + l * 768,
              nullptr, 0, arena, 1024, Mch, 768, DD, 0);
      k_attn<<<c, 256, 0, stream>>>(arena);
      gemm_bf(arena + 768, 1024, wb_o + (size_t)l * 256 * 256, bo + l * 256,
              seqc, DD, seqc, DD, Mch, DD, DD, 0);
      k_ln<<<(Mch + 3) / 4, 256, 0, stream>>>(seqc, Mch, ln1_g + l * 256, ln1_b + l * 256);
      gemm_bf(seqc, DD, wb_f1 + (size_t)l * 1024 * 256, bff1 + l * 1024,
              nullptr, 0, arena, 1024, Mch, 1024, DD, 1);
      gemm_bf(arena, 1024, wb_f2 + (size_t)l * 256 * 1024, bff2 + l * 256,
              seqc, DD, seqc, DD, Mch, DD, 1024, 0);
      k_ln<<<(Mch + 3) / 4, 256, 0, stream>>>(seqc, Mch, ln2_g + l * 256, ln2_b + l * 256);
    }
    k_final<<<(c + 3) / 4, 256, 0, stream>>>(seqc, n0, c, norm_g, norm_b, out);
  }
}

// Round 3
// 3191.239 us; speedup vs baseline: 2.1582x; 1.3193x over previous
//
#include <hip/hip_runtime.h>
#include <hip/hip_bf16.h>

#define NN  50000
#define EE  320000
#define E2  (EE + NN)
#define DIN 128
#define DD  256

typedef __attribute__((ext_vector_type(8))) short    bf16x8;
typedef __attribute__((ext_vector_type(4))) float    f32x4;

// ---------------- helpers ----------------

static __device__ __forceinline__ float bf2f(unsigned short u) {
  return __builtin_bit_cast(float, (unsigned)u << 16);
}

static __device__ __forceinline__ unsigned short f2bf(float f) {
  unsigned u = __builtin_bit_cast(unsigned, f);
  return (unsigned short)((u + 0x7fffu + ((u >> 16) & 1u)) >> 16);
}

static __device__ __forceinline__ void load_lds16(const void* g, void* l) {
  __builtin_amdgcn_global_load_lds(
      (const __attribute__((address_space(1))) void*)g,
      (__attribute__((address_space(3))) void*)l, 16, 0, 0);
}

// ---------------- weight/activation cast fp32 -> bf16 ----------------

__global__ void k_cast(const float* __restrict__ in, unsigned short* __restrict__ out, int n) {
  int i = blockIdx.x * blockDim.x + threadIdx.x;
  if (i >= n) return;
  out[i] = f2bf(in[i]);
}

// ---------------- CSR build ----------------

__global__ void k_deg(const int* __restrict__ ei, int* __restrict__ deg) {
  int i = blockIdx.x * blockDim.x + threadIdx.x;
  if (i >= E2) return;
  int dst = (i < EE) ? ei[EE + i] : (i - EE);
  atomicAdd(&deg[dst], 1);
}

__global__ __launch_bounds__(1024) void k_scan_tile(const int* __restrict__ in,
                                                    int* __restrict__ out,
                                                    int* __restrict__ tsum, int n) {
  __shared__ int sm[1024];
  int tid = threadIdx.x;
  int g = blockIdx.x * 1024 + tid;
  sm[tid] = (g < n) ? in[g] : 0;
  __syncthreads();
  for (int off = 1; off < 1024; off <<= 1) {
    int t = (tid >= off) ? sm[tid - off] : 0;
    __syncthreads();
    sm[tid] += t;
    __syncthreads();
  }
  if (g < n) out[g] = sm[tid];
  if (tid == 1023) tsum[blockIdx.x] = sm[1023];
}

__global__ void k_scan_sums(int* __restrict__ tsum, int nb) {
  int tid = threadIdx.x;           // single wave of 64, nb <= 64
  int v = (tid < nb) ? tsum[tid] : 0;
  for (int off = 1; off < 64; off <<= 1) {
    int t = __shfl_up(v, off);
    if (tid >= off) v += t;
  }
  if (tid < nb) tsum[tid] = v;
}

__global__ void k_scan_add(int* __restrict__ out, const int* __restrict__ tsum, int n) {
  int g = blockIdx.x * blockDim.x + threadIdx.x;
  if (g >= n || g < 1024) return;
  out[g] += tsum[(g >> 10) - 1];
}

__global__ void k_scatter(const int* __restrict__ ei, const int* __restrict__ deg,
                          const int* __restrict__ inc, int* __restrict__ cur,
                          int* __restrict__ ssrc) {
  int i = blockIdx.x * blockDim.x + threadIdx.x;
  if (i >= E2) return;
  int src, dst;
  if (i < EE) { src = ei[i]; dst = ei[EE + i]; } else { src = dst = i - EE; }
  int pos = atomicAdd(&cur[dst], 1);
  ssrc[inc[dst] - deg[dst] + pos] = src;
}

// ---------------- GAT pieces (h is fp32) ----------------

__global__ __launch_bounds__(256) void k_dots(const float* __restrict__ h,
                                              const float* __restrict__ asrc,
                                              const float* __restrict__ adst,
                                              float* __restrict__ hs, float* __restrict__ hd) {
  int node = blockIdx.x * 4 + (threadIdx.x >> 6);
  if (node >= NN) return;
  int lane = threadIdx.x & 63;
  const float* row = h + (size_t)node * DD;
  float s1 = 0.f, s2 = 0.f;
#pragma unroll
  for (int i = 0; i < 4; ++i) {
    float v = row[i * 64 + lane];
    s1 += v * asrc[i * 64 + lane];
    s2 += v * adst[i * 64 + lane];
  }
  for (int off = 32; off; off >>= 1) {
    s1 += __shfl_xor(s1, off);
    s2 += __shfl_xor(s2, off);
  }
  if (lane == 0) { hs[node] = s1; hd[node] = s2; }
}

__global__ void k_esoft(const int* __restrict__ ssrc, const int* __restrict__ deg,
                        const int* __restrict__ inc, const float* __restrict__ hs,
                        const float* __restrict__ hd, float* __restrict__ alpha) {
  int d = blockIdx.x * blockDim.x + threadIdx.x;
  if (d >= NN) return;
  int end = inc[d], cnt = deg[d], base = end - cnt;
  float hdd = hd[d];
  float m = -1e30f;
  for (int i = 0; i < cnt; ++i) {
    float s = hs[ssrc[base + i]] + hdd;
    s = (s < 0.f) ? 0.2f * s : s;
    alpha[base + i] = s;
    m = fmaxf(m, s);
  }
  float sum = 0.f;
  for (int i = 0; i < cnt; ++i) {
    float e = __expf(alpha[base + i] - m);
    alpha[base + i] = e;
    sum += e;
  }
  float inv = 1.f / sum;
  for (int i = 0; i < cnt; ++i) alpha[base + i] *= inv;
}

// aggregates fp32 h rows, writes bf16 x (bias+relu fused)
__global__ __launch_bounds__(256) void k_agg(const float* __restrict__ h,
                                             const int* __restrict__ ssrc,
                                             const int* __restrict__ deg,
                                             const int* __restrict__ inc,
                                             const float* __restrict__ alpha,
                                             const float* __restrict__ bias,
                                             unsigned short* __restrict__ out) {
  int d = blockIdx.x;
  int c = threadIdx.x;
  int end = inc[d], cnt = deg[d], base = end - cnt;
  float acc = 0.f;
  for (int i = 0; i < cnt; ++i) {
    int s = ssrc[base + i];
    float a = alpha[base + i];
    acc += a * h[(size_t)s * DD + c];
  }
  float v = acc + bias[c];
  out[(size_t)d * DD + c] = f2bf(v > 0.f ? v : 0.f);
}

// ---------------- m97-style LDS-staged bf16 MFMA GEMM ----------------
// C = act(A @ B^T + bias [+ R]);  A bf16 [M x K] lda, B bf16 [N x K] (ldb=K),
// C bf16 [M x ldc] or fp32 Cf [M x ldcf]. 128x128 tile, BK=32, 4 waves.

__global__ __launch_bounds__(256) void k_gemm128(
    const unsigned short* __restrict__ A, int lda,
    const unsigned short* __restrict__ B,
    const float* __restrict__ bias,
    const unsigned short* __restrict__ R, int ldr,
    unsigned short* __restrict__ C, int ldc,
    float* __restrict__ Cf, int ldcf,
    int M, int N, int K, int act) {
  __shared__ unsigned short As[128 * 32];
  __shared__ unsigned short Bs[128 * 32];

  const int tid    = threadIdx.x;
  const int lane   = tid & 63;
  const int w      = tid >> 6;
  const int m_lane = lane & 15;
  const int quad   = lane >> 4;
  const int m0     = blockIdx.y * 128;
  const int n0     = blockIdx.x * 128;
  const int wm     = (w >> 1) * 64;
  const int wn     = (w & 1) * 64;

  // staging: idx = round*256 + tid; row = idx>>2, kchunk = idx&3 (16B each)
  const int idx0 = tid, idx1 = 256 + tid;
  int rowA0 = m0 + (idx0 >> 2); if (rowA0 >= M) rowA0 = M - 1;
  int rowA1 = m0 + (idx1 >> 2); if (rowA1 >= M) rowA1 = M - 1;
  const unsigned short* gA0 = A + (size_t)rowA0 * lda + (idx0 & 3) * 8;
  const unsigned short* gA1 = A + (size_t)rowA1 * lda + (idx1 & 3) * 8;
  const unsigned short* gB0 = B + (size_t)(n0 + (idx0 >> 2)) * K + (idx0 & 3) * 8;
  const unsigned short* gB1 = B + (size_t)(n0 + (idx1 >> 2)) * K + (idx1 & 3) * 8;

  // wave-uniform LDS destinations (HW adds lane*16)
  unsigned short* lA0 = As + (size_t)(w * 64) * 8;
  unsigned short* lA1 = As + (size_t)(256 + w * 64) * 8;
  unsigned short* lB0 = Bs + (size_t)(w * 64) * 8;
  unsigned short* lB1 = Bs + (size_t)(256 + w * 64) * 8;

  f32x4 acc[4][4] = {};

  for (int k0 = 0; k0 < K; k0 += 32) {
    load_lds16(gA0, lA0);
    load_lds16(gA1, lA1);
    load_lds16(gB0, lB0);
    load_lds16(gB1, lB1);
    gA0 += 32; gA1 += 32; gB0 += 32; gB1 += 32;
    __syncthreads();   // drains vmcnt, tiles visible

    bf16x8 af[4], bg[4];
#pragma unroll
    for (int i = 0; i < 4; ++i)
      af[i] = *reinterpret_cast<const bf16x8*>(As + (wm + i * 16 + m_lane) * 32 + quad * 8);
#pragma unroll
    for (int j = 0; j < 4; ++j)
      bg[j] = *reinterpret_cast<const bf16x8*>(Bs + (wn + j * 16 + m_lane) * 32 + quad * 8);
#pragma unroll
    for (int i = 0; i < 4; ++i)
#pragma unroll
      for (int j = 0; j < 4; ++j)
        acc[i][j] = __builtin_amdgcn_mfma_f32_16x16x32_bf16(af[i], bg[j], acc[i][j], 0, 0, 0);
    __syncthreads();   // all waves done reading tiles before restage
  }

#pragma unroll
  for (int i = 0; i < 4; ++i) {
#pragma unroll
    for (int j = 0; j < 4; ++j) {
      int col = n0 + wn + j * 16 + m_lane;
      float bv = bias ? bias[col] : 0.f;
#pragma unroll
      for (int r = 0; r < 4; ++r) {
        int row = m0 + wm + i * 16 + quad * 4 + r;
        if (row < M) {
          float v = acc[i][j][r] + bv;
          if (R) v += bf2f(R[(size_t)row * ldr + col]);
          if (act) v = v > 0.f ? v : 0.f;
          if (Cf) Cf[(size_t)row * ldcf + col] = v;
          else    C[(size_t)row * ldc + col] = f2bf(v);
        }
      }
    }
  }
}

// ---------------- transformer pieces (bf16 activations, dense layouts) ----------------

__global__ void k_seqbuild(const unsigned short* __restrict__ x1,
                           const unsigned short* __restrict__ x2,
                           const float* __restrict__ cls, const float* __restrict__ pos,
                           unsigned short* __restrict__ seqc, int n0, int cn) {
  int idx = blockIdx.x * blockDim.x + threadIdx.x;
  int total = cn * 3 * DD;
  if (idx >= total) return;
  int c = idx & (DD - 1);
  int r = idx >> 8;
  int t = r % 3, ln = r / 3;
  int n = n0 + ln;
  float v;
  if (t == 0)      v = cls[c];
  else if (t == 1) v = bf2f(x1[(size_t)n * DD + c]);
  else             v = bf2f(x2[(size_t)n * DD + c]);
  seqc[idx] = f2bf(v + pos[t * DD + c]);
}

// qkv: [3 rows x 768] per node (dense); o -> obuf [3 rows x 256]
__global__ __launch_bounds__(256) void k_attn(const unsigned short* __restrict__ qkvb,
                                              unsigned short* __restrict__ obuf) {
  __shared__ float qkv[3][768];
  __shared__ float lg[4][3][3];
  __shared__ float aw[4][3][3];
  int tid = threadIdx.x;
  size_t r0 = (size_t)blockIdx.x * 3;
  for (int i = tid; i < 3 * 768; i += 256) {
    int r = i / 768, c = i % 768;
    qkv[r][c] = bf2f(qkvb[(r0 + r) * 768 + c]);
  }
  __syncthreads();
  int h = tid >> 6, lane = tid & 63;
#pragma unroll
  for (int ti = 0; ti < 3; ++ti)
#pragma unroll
    for (int j = 0; j < 3; ++j) {
      float p = qkv[ti][h * 64 + lane] * qkv[j][256 + h * 64 + lane];
      for (int off = 32; off; off >>= 1) p += __shfl_xor(p, off);
      if (lane == 0) lg[h][ti][j] = p * 0.125f;
    }
  __syncthreads();
  if (lane < 3) {
    int ti = lane;
    float l0 = lg[h][ti][0], l1 = lg[h][ti][1], l2 = lg[h][ti][2];
    float m = fmaxf(l0, fmaxf(l1, l2));
    float e0 = __expf(l0 - m), e1 = __expf(l1 - m), e2 = __expf(l2 - m);
    float inv = 1.f / (e0 + e1 + e2);
    aw[h][ti][0] = e0 * inv; aw[h][ti][1] = e1 * inv; aw[h][ti][2] = e2 * inv;
  }
  __syncthreads();
  int c = tid;
#pragma unroll
  for (int ti = 0; ti < 3; ++ti) {
    float o = aw[h][ti][0] * qkv[0][512 + c] +
              aw[h][ti][1] * qkv[1][512 + c] +
              aw[h][ti][2] * qkv[2][512 + c];
    obuf[(r0 + ti) * 256 + c] = f2bf(o);
  }
}

__global__ __launch_bounds__(256) void k_ln(unsigned short* __restrict__ buf, int rows,
                                            const float* __restrict__ g,
                                            const float* __restrict__ b) {
  int row = blockIdx.x * 4 + (threadIdx.x >> 6);
  if (row >= rows) return;
  int lane = threadIdx.x & 63;
  unsigned short* p = buf + (size_t)row * DD;
  float v[4];
  float s = 0.f, s2 = 0.f;
#pragma unroll
  for (int i = 0; i < 4; ++i) {
    v[i] = bf2f(p[i * 64 + lane]);
    s += v[i]; s2 += v[i] * v[i];
  }
  for (int off = 32; off; off >>= 1) { s += __shfl_xor(s, off); s2 += __shfl_xor(s2, off); }
  float mean = s * (1.f / 256.f);
  float var  = s2 * (1.f / 256.f) - mean * mean;
  float inv  = rsqrtf(var + 1e-5f);
#pragma unroll
  for (int i = 0; i < 4; ++i) {
    int c = i * 64 + lane;
    p[c] = f2bf((v[i] - mean) * inv * g[c] + b[c]);
  }
}

__global__ __launch_bounds__(256) void k_final(const unsigned short* __restrict__ seqc,
                                               int n0, int cn,
                                               const float* __restrict__ g,
                                               const float* __restrict__ b,
                                               float* __restrict__ out) {
  int ln = blockIdx.x * 4 + (threadIdx.x >> 6);
  if (ln >= cn) return;
  int lane = threadIdx.x & 63;
  const unsigned short* p = seqc + (size_t)ln * 3 * DD;   // token 0 row
  float v[4];
  float s = 0.f, s2 = 0.f;
#pragma unroll
  for (int i = 0; i < 4; ++i) {
    v[i] = bf2f(p[i * 64 + lane]);
    s += v[i]; s2 += v[i] * v[i];
  }
  for (int off = 32; off; off >>= 1) { s += __shfl_xor(s, off); s2 += __shfl_xor(s2, off); }
  float mean = s * (1.f / 256.f);
  float var  = s2 * (1.f / 256.f) - mean * mean;
  float inv  = rsqrtf(var + 1e-5f);
#pragma unroll
  for (int i = 0; i < 4; ++i) {
    int c = i * 64 + lane;
    out[(size_t)(n0 + ln) * DD + c] = (v[i] - mean) * inv * g[c] + b[c];
  }
}

// ---------------- host ----------------

extern "C" void kernel_launch(void* const* d_in, const int* in_sizes, int n_in,
                              void* d_out, int out_size, void* d_ws, size_t ws_size,
                              hipStream_t stream) {
  const float* x       = (const float*)d_in[0];
  const int*   ei      = (const int*)d_in[1];
  const float* gat1_W  = (const float*)d_in[2];
  const float* gat1_b  = (const float*)d_in[3];
  const float* gat1_as = (const float*)d_in[4];
  const float* gat1_ad = (const float*)d_in[5];
  const float* gat2_W  = (const float*)d_in[6];
  const float* gat2_b  = (const float*)d_in[7];
  const float* gat2_as = (const float*)d_in[8];
  const float* gat2_ad = (const float*)d_in[9];
  const float* cls     = (const float*)d_in[10];
  const float* pos     = (const float*)d_in[11];
  const float* Wqkv    = (const float*)d_in[12];
  const float* bqkv    = (const float*)d_in[13];
  const float* Wo      = (const float*)d_in[14];
  const float* bo      = (const float*)d_in[15];
  const float* ln1_g   = (const float*)d_in[16];
  const float* ln1_b   = (const float*)d_in[17];
  const float* ln2_g   = (const float*)d_in[18];
  const float* ln2_b   = (const float*)d_in[19];
  const float* Wff1    = (const float*)d_in[20];
  const float* bff1    = (const float*)d_in[21];
  const float* Wff2    = (const float*)d_in[22];
  const float* bff2    = (const float*)d_in[23];
  const float* norm_g  = (const float*)d_in[24];
  const float* norm_b  = (const float*)d_in[25];
  float* out = (float*)d_out;

  char* ws = (char*)d_ws;
  size_t off = 0;
  auto alloc = [&](size_t bytes) -> void* {
    off = (off + 255) & ~(size_t)255;
    void* p = ws + off;
    off += bytes;
    return p;
  };

  unsigned short* wb_g1  = (unsigned short*)alloc(sizeof(unsigned short) * 256 * 128);
  unsigned short* wb_g2  = (unsigned short*)alloc(sizeof(unsigned short) * 256 * 256);
  unsigned short* wb_qkv = (unsigned short*)alloc(sizeof(unsigned short) * 2 * 768 * 256);
  unsigned short* wb_o   = (unsigned short*)alloc(sizeof(unsigned short) * 2 * 256 * 256);
  unsigned short* wb_f1  = (unsigned short*)alloc(sizeof(unsigned short) * 2 * 1024 * 256);
  unsigned short* wb_f2  = (unsigned short*)alloc(sizeof(unsigned short) * 2 * 256 * 1024);
  unsigned short* xb  = (unsigned short*)alloc(sizeof(unsigned short) * (size_t)NN * DIN);
  float*          h   = (float*)alloc(sizeof(float) * (size_t)NN * DD);
  unsigned short* x1b = (unsigned short*)alloc(sizeof(unsigned short) * (size_t)NN * DD);
  unsigned short* x2b = (unsigned short*)alloc(sizeof(unsigned short) * (size_t)NN * DD);
  float* hs  = (float*)alloc(sizeof(float) * NN);
  float* hd  = (float*)alloc(sizeof(float) * NN);
  int* deg   = (int*)alloc(sizeof(int) * NN);
  int* inc   = (int*)alloc(sizeof(int) * NN);
  int* cur   = (int*)alloc(sizeof(int) * NN);
  int* tsum  = (int*)alloc(sizeof(int) * 64);
  int* ssrc  = (int*)alloc(sizeof(int) * E2);
  float* alpha = (float*)alloc(sizeof(float) * E2);

  // transformer chunking: keep per-chunk activations L3-resident (~173 MB @ 12500)
  size_t fixed = (off + 255) & ~(size_t)255;
  size_t rem = (ws_size > fixed + 4096) ? (ws_size - fixed - 4096) : 0;
  const size_t per_node = (size_t)3 * (256 + 768 + 256 + 1024) * 2;
  size_t cn_max = rem / per_node;
  if (cn_max < 1) cn_max = 1;
  if (cn_max > 12500) cn_max = 12500;
  int nc = (int)((NN + cn_max - 1) / cn_max);
  int cn = (NN + nc - 1) / nc;
  unsigned short* seqc = (unsigned short*)alloc(sizeof(unsigned short) * (size_t)3 * cn * 256);
  unsigned short* qkvb = (unsigned short*)alloc(sizeof(unsigned short) * (size_t)3 * cn * 768);
  unsigned short* obuf = (unsigned short*)alloc(sizeof(unsigned short) * (size_t)3 * cn * 256);
  unsigned short* ffb  = (unsigned short*)alloc(sizeof(unsigned short) * (size_t)3 * cn * 1024);

  // ---- casts ----
  auto cast = [&](const float* src, unsigned short* dst, int n) {
    k_cast<<<(n + 255) / 256, 256, 0, stream>>>(src, dst, n);
  };
  cast(gat1_W, wb_g1, 256 * 128);
  cast(gat2_W, wb_g2, 256 * 256);
  cast(Wqkv, wb_qkv, 2 * 768 * 256);
  cast(Wo, wb_o, 2 * 256 * 256);
  cast(Wff1, wb_f1, 2 * 1024 * 256);
  cast(Wff2, wb_f2, 2 * 256 * 1024);
  cast(x, xb, NN * DIN);

  // ---- CSR build ----
  hipMemsetAsync(deg, 0, sizeof(int) * NN, stream);
  hipMemsetAsync(cur, 0, sizeof(int) * NN, stream);
  k_deg<<<(E2 + 255) / 256, 256, 0, stream>>>(ei, deg);
  int nb = (NN + 1023) / 1024;
  k_scan_tile<<<nb, 1024, 0, stream>>>(deg, inc, tsum, NN);
  k_scan_sums<<<1, 64, 0, stream>>>(tsum, nb);
  k_scan_add<<<(NN + 255) / 256, 256, 0, stream>>>(inc, tsum, NN);
  k_scatter<<<(E2 + 255) / 256, 256, 0, stream>>>(ei, deg, inc, cur, ssrc);

  auto gemm = [&](const unsigned short* A, int lda, const unsigned short* B,
                  const float* bias, const unsigned short* R, int ldr,
                  unsigned short* C, int ldc, float* Cf, int ldcf,
                  int M, int N, int K, int act) {
    dim3 grid(N / 128, (M + 127) / 128);
    k_gemm128<<<grid, 256, 0, stream>>>(A, lda, B, bias, R, ldr, C, ldc, Cf, ldcf,
                                        M, N, K, act);
  };

  // ---- GAT layer 1 ----
  gemm(xb, DIN, wb_g1, nullptr, nullptr, 0, nullptr, 0, h, DD, NN, DD, DIN, 0);
  k_dots<<<(NN + 3) / 4, 256, 0, stream>>>(h, gat1_as, gat1_ad, hs, hd);
  k_esoft<<<(NN + 255) / 256, 256, 0, stream>>>(ssrc, deg, inc, hs, hd, alpha);
  k_agg<<<NN, 256, 0, stream>>>(h, ssrc, deg, inc, alpha, gat1_b, x1b);

  // ---- GAT layer 2 ----
  gemm(x1b, DD, wb_g2, nullptr, nullptr, 0, nullptr, 0, h, DD, NN, DD, DD, 0);
  k_dots<<<(NN + 3) / 4, 256, 0, stream>>>(h, gat2_as, gat2_ad, hs, hd);
  k_esoft<<<(NN + 255) / 256, 256, 0, stream>>>(ssrc, deg, inc, hs, hd, alpha);
  k_agg<<<NN, 256, 0, stream>>>(h, ssrc, deg, inc, alpha, gat2_b, x2b);

  // ---- transformer (chunked; chunk activations stay L3-resident) ----
  for (int n0 = 0; n0 < NN; n0 += cn) {
    int c = NN - n0 < cn ? NN - n0 : cn;
    int Mch = 3 * c;
    k_seqbuild<<<(c * 3 * DD + 255) / 256, 256, 0, stream>>>(x1b, x2b, cls, pos, seqc, n0, c);
    for (int l = 0; l < 2; ++l) {
      gemm(seqc, DD, wb_qkv + (size_t)l * 768 * 256, bqkv + l * 768,
           nullptr, 0, qkvb, 768, nullptr, 0, Mch, 768, DD, 0);
      k_attn<<<c, 256, 0, stream>>>(qkvb, obuf);
      gemm(obuf, DD, wb_o + (size_t)l * 256 * 256, bo + l * 256,
           seqc, DD, seqc, DD, nullptr, 0, Mch, DD, DD, 0);
      k_ln<<<(Mch + 3) / 4, 256, 0, stream>>>(seqc, Mch, ln1_g + l * 256, ln1_b + l * 256);
      gemm(seqc, DD, wb_f1 + (size_t)l * 1024 * 256, bff1 + l * 1024,
           nullptr, 0, ffb, 1024, nullptr, 0, Mch, 1024, DD, 1);
      gemm(ffb, 1024, wb_f2 + (size_t)l * 256 * 1024, bff2 + l * 256,
           seqc, DD, seqc, DD, nullptr, 0, Mch, DD, 1024, 0);
      k_ln<<<(Mch + 3) / 4, 256, 0, stream>>>(seqc, Mch, ln2_g + l * 256, ln2_b + l * 256);
    }
    k_final<<<(c + 3) / 4, 256, 0, stream>>>(seqc, n0, c, norm_g, norm_b, out);
  }
}